// Round 1
// baseline (138.703 us; speedup 1.0000x reference)
//
#include <hip/hip_runtime.h>

// Problem constants (fixed by the reference).
#define BATCH 16384
#define DIN   128
#define HIDN  16
#define NNODE 255
#define NLEAF 256

typedef _Float16 half8 __attribute__((ext_vector_type(8)));
typedef float   float4v __attribute__((ext_vector_type(4)));

// ---------------- pack x -> f16 B-operand fragments ----------------
// B-frag layout for v_mfma_f32_16x16x32_f16: lane L holds B[k=(L>>4)*8+j][n=L&15].
// ws layout: [bt(1024)][kc(4)][lane(64)] -> half8 (16B), value[j] = x[bt*16+(L&15)][kc*32+(L>>4)*8+j]
__global__ __launch_bounds__(256) void k_pack_x(const float* __restrict__ x, half8* __restrict__ xp) {
    int gid  = blockIdx.x * 256 + threadIdx.x;   // 1024*4*64 = 262144 total
    int lane = gid & 63;
    int kc   = (gid >> 6) & 3;
    int bt   = gid >> 8;
    const float* src = x + (size_t)(bt * 16 + (lane & 15)) * DIN + kc * 32 + ((lane >> 4) * 8);
    half8 v;
#pragma unroll
    for (int j = 0; j < 8; ++j) v[j] = (_Float16)src[j];
    xp[gid] = v;
}

// ---------------- pack W1 -> f16 A-operand fragments ----------------
// A-frag layout: lane L holds A[m=L&15][k=(L>>4)*8+j]; here m = hidden unit h, k = input i.
// ws layout: [n(255)][kc(4)][lane(64)] -> half8, value[j] = W1[n][kc*32+(L>>4)*8+j][L&15]
__global__ __launch_bounds__(256) void k_pack_w1(const float* __restrict__ w1, half8* __restrict__ w1p) {
    int gid = blockIdx.x * 256 + threadIdx.x;    // 255*4*64 = 65280 total
    if (gid >= NNODE * 4 * 64) return;
    int lane = gid & 63;
    int kc   = (gid >> 6) & 3;
    int n    = gid >> 8;
    const float* src = w1 + (size_t)n * (DIN * HIDN) + (size_t)(kc * 32 + (lane >> 4) * 8) * HIDN + (lane & 15);
    half8 v;
#pragma unroll
    for (int j = 0; j < 8; ++j) v[j] = (_Float16)src[j * HIDN];
    w1p[gid] = v;
}

// ---------------- fused MLP: p = sigmoid(relu(x@W1 + b1) @ W2 + b2) ----------------
// Orientation: A = W1 (m=h), B = x^T (n=batch). C layout: row(m)=h=(L>>4)*4+reg, col(n)=batch=L&15.
// Per wave: 4 resident batch-tiles (64 VGPR of x frags), loop over 15 nodes.
// Grid: (64 batch-groups of 16 tiles) x (17 node-groups of 15). 255 = 15*17, 1024 = 64*16 exact.
__global__ __launch_bounds__(256) void k_mlp(const half8* __restrict__ xp, const half8* __restrict__ w1p,
                                             const float* __restrict__ b1, const float* __restrict__ w2,
                                             const float* __restrict__ b2, float* __restrict__ p_out) {
    int wave = threadIdx.x >> 6;
    int lane = threadIdx.x & 63;
    int q    = lane >> 4;       // quad: h = q*4 + reg
    int c    = lane & 15;       // batch column within tile
    int bt0  = blockIdx.x * 16 + wave * 4;
    int n0   = blockIdx.y * 15;

    half8 bq[4][4];
#pragma unroll
    for (int t = 0; t < 4; ++t)
#pragma unroll
        for (int kc = 0; kc < 4; ++kc)
            bq[t][kc] = xp[(size_t)((bt0 + t) * 4 + kc) * 64 + lane];

    for (int i = 0; i < 15; ++i) {
        int n = n0 + i;
        half8 a[4];
#pragma unroll
        for (int kc = 0; kc < 4; ++kc) a[kc] = w1p[(size_t)(n * 4 + kc) * 64 + lane];
        float b1f[4], w2f[4];
#pragma unroll
        for (int r = 0; r < 4; ++r) {
            b1f[r] = b1[n * HIDN + q * 4 + r];
            w2f[r] = w2[n * HIDN + q * 4 + r];
        }
        float b2v = b2[n];
#pragma unroll
        for (int t = 0; t < 4; ++t) {
            float4v acc = {b1f[0], b1f[1], b1f[2], b1f[3]};   // bias folded into accumulator init
#pragma unroll
            for (int kc = 0; kc < 4; ++kc)
                acc = __builtin_amdgcn_mfma_f32_16x16x32_f16(a[kc], bq[t][kc], acc, 0, 0, 0);
            // epilogue: relu, weight by W2 over the 4 h's this lane holds, reduce across quads
            float s = 0.f;
#pragma unroll
            for (int r = 0; r < 4; ++r) s = fmaf(fmaxf(acc[r], 0.f), w2f[r], s);
            s += __shfl_xor(s, 16, 64);
            s += __shfl_xor(s, 32, 64);
            float logit = s + b2v;
            float pv = 1.f / (1.f + __expf(-logit));
            if (lane < 16) p_out[(size_t)((bt0 + t) * 16 + c) * NNODE + n] = pv;
        }
    }
}

// ---------------- tree scan: path_probs, node_reach, h ----------------
// One wave per row. Lane L owns leaves 4L..4L+3 (top-6-level prefix shared).
// Leaf j bits: level l uses bit (7-l); node at level l = 2^l - 1 + (j >> (8-l)).
__global__ __launch_bounds__(256) void k_tree(const float* __restrict__ p_all, const float* __restrict__ leaf,
                                              float* __restrict__ h_out, float* __restrict__ pp_out,
                                              float* __restrict__ nr_out) {
    __shared__ float sp[4][NLEAF];
    int wave = threadIdx.x >> 6;
    int lane = threadIdx.x & 63;
    int b = blockIdx.x * 4 + wave;
    const float* prow = p_all + (size_t)b * NNODE;
#pragma unroll
    for (int s = 0; s < 4; ++s) {
        int idx = lane + 64 * s;
        if (idx < NNODE) sp[wave][idx] = prow[idx];
    }
    __syncthreads();
    const float* P = sp[wave];
    float* nr = nr_out + (size_t)b * NNODE;

    float pref = 1.f;   // reach prob of current node on the path to leaf 4*lane
#pragma unroll
    for (int l = 0; l < 6; ++l) {
        // first lane of each subtree writes node_reach for this level
        if ((lane & ((1 << (6 - l)) - 1)) == 0) nr[(1 << l) - 1 + (lane >> (6 - l))] = pref;
        float pv  = P[(1 << l) - 1 + (lane >> (6 - l))];
        int  bit  = (lane >> (5 - l)) & 1;
        pref *= bit ? pv : (1.f - pv);
    }
    nr[63 + lane] = pref;            // level-6 node reach (one per lane)
    float p6 = P[63 + lane];
    float pl = pref * (1.f - p6);
    float pr = pref * p6;
    nr[127 + 2 * lane] = pl;         // level-7 reach, left child
    nr[128 + 2 * lane] = pr;         // level-7 reach, right child
    float p7a = P[127 + 2 * lane];
    float p7b = P[128 + 2 * lane];
    float4 pp;
    pp.x = pl * (1.f - p7a);
    pp.y = pl * p7a;
    pp.z = pr * (1.f - p7b);
    pp.w = pr * p7b;
    *(float4*)(pp_out + (size_t)b * NLEAF + 4 * lane) = pp;   // coalesced 16B store
    const float4 lf = *(const float4*)(leaf + 4 * lane);
    float hs = pp.x * lf.x + pp.y * lf.y + pp.z * lf.z + pp.w * lf.w;
#pragma unroll
    for (int off = 1; off < 64; off <<= 1) hs += __shfl_xor(hs, off, 64);
    if (lane == 0) h_out[b] = hs;
}

extern "C" void kernel_launch(void* const* d_in, const int* in_sizes, int n_in,
                              void* d_out, int out_size, void* d_ws, size_t ws_size,
                              hipStream_t stream) {
    const float* x    = (const float*)d_in[0];
    const float* W1   = (const float*)d_in[1];
    const float* b1   = (const float*)d_in[2];
    const float* W2   = (const float*)d_in[3];
    const float* b2   = (const float*)d_in[4];
    const float* leaf = (const float*)d_in[5];

    float* out    = (float*)d_out;
    float* h_out  = out;                                   // [16384]
    float* pp_out = out + BATCH;                           // [16384*256]
    float* p_out  = pp_out + (size_t)BATCH * NLEAF;        // [16384*255]
    float* nr_out = p_out + (size_t)BATCH * NNODE;         // [16384*255]

    // workspace: 4 MB packed x + ~1 MB packed W1 (needs ~5.05 MB of d_ws)
    half8* xp  = (half8*)d_ws;
    half8* w1p = xp + (size_t)1024 * 4 * 64;

    hipLaunchKernelGGL(k_pack_x,  dim3(1024),      dim3(256), 0, stream, x, xp);
    hipLaunchKernelGGL(k_pack_w1, dim3(255),       dim3(256), 0, stream, W1, w1p);
    hipLaunchKernelGGL(k_mlp,     dim3(64, 17),    dim3(256), 0, stream, xp, w1p, b1, W2, b2, p_out);
    hipLaunchKernelGGL(k_tree,    dim3(BATCH / 4), dim3(256), 0, stream, p_out, leaf, h_out, pp_out, nr_out);
}